// Round 6
// baseline (4022.833 us; speedup 1.0000x reference)
//
#include <hip/hip_runtime.h>
#include <math.h>

#define T_STEPS 64
#define BATCH   32
#define SEQ     64
#define HID     512
#define VOCAB   32000
#define ABASE   16000   // outs (A-matrix) band: f32 cols [16000,16512) of each logits row
#define SBASE   16512   // fp32 state band: f32 cols [16512,16576)
#define NBLK    256

typedef unsigned short u16;
typedef unsigned int   u32;

typedef __attribute__((ext_vector_type(8))) short short8;
typedef __attribute__((ext_vector_type(4))) float f32x4;

#define AS_RLX __ATOMIC_RELAXED
#define SC_AGT __HIP_MEMORY_SCOPE_AGENT

__device__ __forceinline__ u16 f2bf(float f) {
  u32 x = __float_as_uint(f);
  u32 r = (x + 0x7fffu + ((x >> 16) & 1u)) >> 16;
  return (u16)r;
}
__device__ __forceinline__ float sigf(float x) { return 1.0f / (1.0f + expf(-x)); }

// fp32 state element i lives at logits row (i>>6), f32 col SBASE + (i&63).
__device__ __forceinline__ float* stP(float* o, int i) {
  return o + (size_t)(i >> 6) * VOCAB + SBASE + (i & 63);
}
// state map (floats): h0 bufs @ 0/16384 (h0(t) in buf[t&1]);
//                     h1 bufs @ 32768/49152 (h1(t) in buf[t&1]);
//                     q bufs @ 65536/81920 (q(s) in buf[s&1]);
//                     ctx bufs @ 98304/114688 (ctx(s) in buf[s&1]).

// ---- coherent (agent-scope, L2-bypassing) band accessors -------------------
__device__ __forceinline__ void bst(float* p, float v) {
  __hip_atomic_store(p, v, AS_RLX, SC_AGT);
}
__device__ __forceinline__ float bld(const float* p) {
  return __hip_atomic_load(p, AS_RLX, SC_AGT);
}
__device__ __forceinline__ float4 bld4(const float* p) {
  float4 r;
  r.x = __hip_atomic_load(p + 0, AS_RLX, SC_AGT);
  r.y = __hip_atomic_load(p + 1, AS_RLX, SC_AGT);
  r.z = __hip_atomic_load(p + 2, AS_RLX, SC_AGT);
  r.w = __hip_atomic_load(p + 3, AS_RLX, SC_AGT);
  return r;
}

// sync word i -> logits rows 0..5, cols 17024.. (overwritten later by gemm_a)
__device__ __forceinline__ unsigned* syncW(float* o, int i) {
  return (unsigned*)(o + (size_t)(i >> 6) * VOCAB + 17024 + (i & 63));
}

// spin until *w >= g; self-healing periodic fence prevents any livelock.
__device__ __forceinline__ void spin_until(unsigned* w, unsigned g) {
  int k = 0;
  while (__hip_atomic_load(w, AS_RLX, SC_AGT) < g) {
    __builtin_amdgcn_s_sleep(2);
    if (++k == 16384) { k = 0; __threadfence(); }
  }
}

// fence-free grid barrier (state is sc1 write-through; release = vmcnt drain).
__device__ __forceinline__ void gsync(float* o, unsigned g) {
  asm volatile("s_waitcnt vmcnt(0)" ::: "memory");
  __syncthreads();
  const int tid = threadIdx.x;
  if (blockIdx.x == 0) {
    if (tid >= 1) spin_until(syncW(o, tid), g);
    __syncthreads();
    if (tid == 0)
      __hip_atomic_store(syncW(o, 320), g, AS_RLX, SC_AGT);
  } else {
    if (tid == 0) {
      __hip_atomic_store(syncW(o, blockIdx.x), g, AS_RLX, SC_AGT);
      spin_until(syncW(o, 320), g);
    }
  }
  __syncthreads();
}

// ---------------------------------------------------------------------------
// xs staging: 32 batches x 512 floats as float4 slots [k4][b], XOR-swizzled.
// ---------------------------------------------------------------------------
__device__ __forceinline__ int xslot(int k4, int bb) {
  return (k4 * 32 + (bb ^ (k4 & 7))) * 4;
}
__device__ __forceinline__ void stage_band(float* o, int base, float* xs) {
  const int tid = threadIdx.x;
#pragma unroll
  for (int it = 0; it < 16; ++it) {
    int f = it * 256 + tid;
    int bb = f >> 7, k4 = f & 127;
    *(float4*)&xs[xslot(k4, bb)] = bld4(stP(o, base + bb * 512 + k4 * 4));
  }
}
__device__ __forceinline__ void stage_emb(const int* __restrict__ tokens,
                                          const float* __restrict__ emb,
                                          int t, float* xs) {
  const int tid = threadIdx.x;
#pragma unroll
  for (int it = 0; it < 16; ++it) {
    int f = it * 256 + tid;
    int bb = f >> 7, k4 = f & 127;
    int tok = tokens[bb * T_STEPS + t];
    *(float4*)&xs[xslot(k4, bb)] = *(const float4*)(emb + (size_t)tok * HID + k4 * 4);
  }
}

// ---------------------------------------------------------------------------
// pair-dot helpers. Thread (kh,q,b): rows q*2 and q*2+1, k in [kh*256, +256).
// W matrices are 8x512 row-major in LDS; W-reads are 2-address broadcasts.
// ---------------------------------------------------------------------------
__device__ __forceinline__ void dotPH(const float* xs, const float* W,
                                      int kh, int q, int b, float& r0, float& r1) {
  const float* w0 = W + (q * 2) * 512 + kh * 256;
  const float* w1 = w0 + 512;
  const int k0 = kh * 64;
  float a0 = 0.f, a1 = 0.f, a2 = 0.f, a3 = 0.f;
#pragma unroll 8
  for (int i = 0; i < 64; ++i) {
    float4 x = *(const float4*)&xs[xslot(k0 + i, b)];
    float4 u = *(const float4*)&w0[i * 4];
    float4 v = *(const float4*)&w1[i * 4];
    a0 += u.x * x.x + u.y * x.y; a1 += u.z * x.z + u.w * x.w;
    a2 += v.x * x.x + v.y * x.y; a3 += v.z * x.z + v.w * x.w;
  }
  r0 += a0 + a1; r1 += a2 + a3;
}
// fused: two matrices (Wa->ra, Wb->rb) from ONE X pass
__device__ __forceinline__ void dotPH2(const float* xs, const float* Wa, const float* Wb,
                                       int kh, int q, int b,
                                       float& ra0, float& ra1, float& rb0, float& rb1) {
  const float* wa0 = Wa + (q * 2) * 512 + kh * 256; const float* wa1 = wa0 + 512;
  const float* wb0 = Wb + (q * 2) * 512 + kh * 256; const float* wb1 = wb0 + 512;
  const int k0 = kh * 64;
  float p0 = 0.f, p1 = 0.f, p2 = 0.f, p3 = 0.f;
  float s0 = 0.f, s1 = 0.f, s2 = 0.f, s3 = 0.f;
#pragma unroll 8
  for (int i = 0; i < 64; ++i) {
    float4 x = *(const float4*)&xs[xslot(k0 + i, b)];
    float4 u = *(const float4*)&wa0[i * 4];
    float4 v = *(const float4*)&wa1[i * 4];
    p0 += u.x * x.x + u.y * x.y; p1 += u.z * x.z + u.w * x.w;
    p2 += v.x * x.x + v.y * x.y; p3 += v.z * x.z + v.w * x.w;
    float4 u2 = *(const float4*)&wb0[i * 4];
    float4 v2 = *(const float4*)&wb1[i * 4];
    s0 += u2.x * x.x + u2.y * x.y; s1 += u2.z * x.z + u2.w * x.w;
    s2 += v2.x * x.x + v2.y * x.y; s3 += v2.z * x.z + v2.w * x.w;
  }
  ra0 += p0 + p1; ra1 += p2 + p3; rb0 += s0 + s1; rb1 += s2 + s3;
}
// seg-dot: 2 explicit row pointers (512-float rows), seg of 16 float4 (64 k).
__device__ __forceinline__ void dotSeg(const float* xs, const float* w0, const float* w1,
                                       int seg, int b, float& r0, float& r1) {
  const int k0 = seg * 16;
  float a0 = 0.f, a1 = 0.f, a2 = 0.f, a3 = 0.f;
#pragma unroll 8
  for (int i = 0; i < 16; ++i) {
    float4 x = *(const float4*)&xs[xslot(k0 + i, b)];
    float4 u = *(const float4*)&w0[(k0 + i) * 4];
    float4 v = *(const float4*)&w1[(k0 + i) * 4];
    a0 += u.x * x.x + u.y * x.y; a1 += u.z * x.z + u.w * x.w;
    a2 += v.x * x.x + v.y * x.y; a3 += v.z * x.z + v.w * x.w;
  }
  r0 = a0 + a1; r1 = a2 + a3;
}

// gate tail over kh-split partials: glx[kh*256 + (q*2+du)*32 + b], bias in tail.
__device__ __forceinline__ void gate_tail2(float* o, const float* glx, const float* bs,
                                           float* cs, int bk, int hout_base, int tl) {
  int b2 = tl & 31, du = tl >> 5, u = bk * 2 + du;
  float gi = glx[(0 + du) * 32 + b2] + glx[256 + (0 + du) * 32 + b2] + bs[0 + du];
  float gf = glx[(2 + du) * 32 + b2] + glx[256 + (2 + du) * 32 + b2] + bs[2 + du];
  float gg = glx[(4 + du) * 32 + b2] + glx[256 + (4 + du) * 32 + b2] + bs[4 + du];
  float go = glx[(6 + du) * 32 + b2] + glx[256 + (6 + du) * 32 + b2] + bs[6 + du];
  float iv = sigf(gi), fv = sigf(gf), gv = tanhf(gg), ov = sigf(go);
  float cn = fv * cs[du * 32 + b2] + iv * gv;
  cs[du * 32 + b2] = cn;
  bst(stP(o, hout_base + b2 * 512 + u), ov * tanhf(cn));
}

// ---------------------------------------------------------------------------
// Persistent kernel: all 64 timesteps, ONE grid barrier per step.
// Thread map: tid = kh*128 + q*32 + b. Each thread computes 2 gate rows over
// its k-half; partials reduced via small LDS buffers in the tails.
// ---------------------------------------------------------------------------
#define SMEM_FLOATS 38864
#define SMEM_BYTES  (SMEM_FLOATS * 4)

__global__ void __launch_bounds__(256, 1) persist_kernel(
    float* o, const int* __restrict__ tokens, const float* __restrict__ emb,
    const float* __restrict__ Wih, const float* __restrict__ Whh,
    const float* __restrict__ bih, const float* __restrict__ bhh,
    const float* __restrict__ Wai, const float* __restrict__ Wao,
    const float* __restrict__ h0in, const float* __restrict__ c0in,
    const float* __restrict__ context,
    float* __restrict__ o_h, float* __restrict__ o_c, float* __restrict__ o_attn)
{
  extern __shared__ float smem[];
  float* wih0  = smem;            // 8*512
  float* whh0  = smem + 4096;
  float* wih1  = smem + 8192;
  float* whh1  = smem + 12288;
  float* waiL  = smem + 16384;    // 2*512
  float* waoL  = smem + 17408;    // 2*1024
  float* xs    = smem + 19456;    // 16384 staged input vectors
  float* glL1  = smem + 35840;    // 512 (L1 partials / attn scores)
  float* glL0  = smem + 36352;    // 512 (L0 partials)
  float* glq   = smem + 36864;    // 512 (q partials)
  float* glo2  = smem + 37376;    // 512 (oph partials)
  float* gloC  = smem + 37888;    // 512 (out-ctx partials / attn ctx partials)
  float* oph   = smem + 38400;    // 2*128 (out h1-half, alternating)
  float* c0s   = smem + 38656;    // 64
  float* c1s   = smem + 38720;    // 64
  float* bias0 = smem + 38784;    // 8
  float* bias1 = smem + 38792;    // 8
  float* at_s  = smem + 38800;    // 64

  const int tid = threadIdx.x;
  const int bk  = blockIdx.x;
  const int b   = tid & 31;
  const int q   = (tid >> 5) & 3;
  const int kh  = tid >> 7;
  unsigned g = 0;

  // ---- load persistent weights into LDS (once) ----
  for (int f = tid; f < 1024; f += 256) {        // 8 rows x 128 float4 each
    int r = f >> 7, k4 = f & 127;
    size_t j0 = (size_t)((r >> 1) * HID + bk * 2 + (r & 1));
    *(float4*)&wih0[r * 512 + k4 * 4] = *(const float4*)(Wih + j0 * HID + k4 * 4);
    *(float4*)&whh0[r * 512 + k4 * 4] = *(const float4*)(Whh + j0 * HID + k4 * 4);
    *(float4*)&wih1[r * 512 + k4 * 4] = *(const float4*)(Wih + 1048576 + j0 * HID + k4 * 4);
    *(float4*)&whh1[r * 512 + k4 * 4] = *(const float4*)(Whh + 1048576 + j0 * HID + k4 * 4);
  }
  {
    int r = tid >> 7, k4 = tid & 127;            // wai: 2 rows x 128 float4
    *(float4*)&waiL[r * 512 + k4 * 4] =
        *(const float4*)(Wai + (size_t)(bk * 2 + r) * HID + k4 * 4);
  }
  for (int f = tid; f < 512; f += 256) {         // wao: 2 rows x 256 float4
    int r = f >> 8, k4 = f & 255;
    *(float4*)&waoL[r * 1024 + k4 * 4] =
        *(const float4*)(Wao + (size_t)(bk * 2 + r) * 2 * HID + k4 * 4);
  }
  if (tid < 8) {
    int j0 = (tid >> 1) * HID + bk * 2 + (tid & 1);
    bias0[tid] = bih[j0] + bhh[j0];
    bias1[tid] = bih[2048 + j0] + bhh[2048 + j0];
  }
  // ---- P0: c state to LDS, h(-1) into buf1 bands ----
  if (tid < 64) {
    int b2 = tid & 31, du = tid >> 5, u = bk * 2 + du;
    c0s[du * 32 + b2] = c0in[b2 * 512 + u];
    c1s[du * 32 + b2] = c0in[16384 + b2 * 512 + u];
    bst(stP(o, 16384 + b2 * 512 + u), h0in[b2 * 512 + u]);          // h0(-1)
    bst(stP(o, 49152 + b2 * 512 + u), h0in[16384 + b2 * 512 + u]);  // h1(-1)
  }
  gsync(o, ++g);

  // ---- P1: L0(0) -> h0(0) (buf0) ----
  {
    float a0 = 0.f, a1 = 0.f;
    stage_emb(tokens, emb, 0, xs); __syncthreads();
    dotPH(xs, wih0, kh, q, b, a0, a1);
    __syncthreads();
    stage_band(o, 16384, xs); __syncthreads();                    // h0(-1)
    dotPH(xs, whh0, kh, q, b, a0, a1);
    glL0[kh * 256 + (q * 2 + 0) * 32 + b] = a0;
    glL0[kh * 256 + (q * 2 + 1) * 32 + b] = a1;
    __syncthreads();
    if (tid >= 64 && tid < 128) gate_tail2(o, glL0, bias0, c0s, bk, 0, tid - 64);
    gsync(o, ++g);
  }

  for (int t = 0; t <= T_STEPS + 2; ++t) {       // t = 0..66
    const int seg = kh * 4 + q;
    // ===== finish out(t-3): ctx-half segments + oph =====
    if (t >= 3) {
      stage_band(o, 98304 + ((t + 1) & 1) * 16384, xs); __syncthreads(); // ctx(t-3)
      float r0, r1;
      dotSeg(xs, waoL, waoL + 1024, seg, b, r0, r1);
      gloC[(0 * 8 + seg) * 32 + b] = r0;
      gloC[(1 * 8 + seg) * 32 + b] = r1;
      __syncthreads();
      if (tid < 64) {
        int du = tid >> 5, b2 = tid & 31;
        float s = 0.f;
#pragma unroll
        for (int sg = 0; sg < 8; ++sg) s += gloC[(du * 8 + sg) * 32 + b2];
        s += oph[((t - 3) & 1) * 128 + du * 32 + b2];
        o[(size_t)((t - 3) * BATCH + b2) * VOCAB + ABASE + bk * 2 + du] = tanhf(s);
      }
      __syncthreads();
    }
    float a0_0 = 0.f, a0_1 = 0.f, a1_0 = 0.f, a1_1 = 0.f;
    // ===== L0(t+1) part 1: wih0 . emb(t+1) =====
    if (t + 1 < T_STEPS) {
      stage_emb(tokens, emb, t + 1, xs); __syncthreads();
      dotPH(xs, wih0, kh, q, b, a0_0, a0_1);
      __syncthreads();
    }
    // ===== h0(t) pass: whh0 (a0) + wih1 (a1), one X pass =====
    if (t < T_STEPS) {
      stage_band(o, (t & 1) * 16384, xs); __syncthreads();
      if (t + 1 < T_STEPS)
        dotPH2(xs, whh0, wih1, kh, q, b, a0_0, a0_1, a1_0, a1_1);
      else
        dotPH(xs, wih1, kh, q, b, a1_0, a1_1);
      __syncthreads();
    }
    // ===== h1(t-1) pass: whh1 (a1) + wai/wao-h1 segment dots =====
    if (t <= T_STEPS) {
      stage_band(o, 32768 + ((t + 1) & 1) * 16384, xs); __syncthreads();
      if (t < T_STEPS) dotPH(xs, whh1, kh, q, b, a1_0, a1_1);
      if (t >= 1) {
        float r0, r1;
        dotSeg(xs, waiL, waiL + 512, seg, b, r0, r1);
        glq[(0 * 8 + seg) * 32 + b] = r0;
        glq[(1 * 8 + seg) * 32 + b] = r1;
        dotSeg(xs, waoL + 512, waoL + 1536, seg, b, r0, r1);
        glo2[(0 * 8 + seg) * 32 + b] = r0;
        glo2[(1 * 8 + seg) * 32 + b] = r1;
      }
    }
    // ===== publish partials; tails =====
    glL1[kh * 256 + (q * 2 + 0) * 32 + b] = a1_0;
    glL1[kh * 256 + (q * 2 + 1) * 32 + b] = a1_1;
    glL0[kh * 256 + (q * 2 + 0) * 32 + b] = a0_0;
    glL0[kh * 256 + (q * 2 + 1) * 32 + b] = a0_1;
    __syncthreads();
    if (tid < 64) {
      if (t < T_STEPS)
        gate_tail2(o, glL1, bias1, c1s, bk, 32768 + (t & 1) * 16384, tid);      // h1(t)
    } else if (tid < 128) {
      if (t + 1 < T_STEPS)
        gate_tail2(o, glL0, bias0, c0s, bk, ((t + 1) & 1) * 16384, tid - 64);   // h0(t+1)
    } else if (tid < 192) {
      if (t >= 1 && t <= T_STEPS) {
        int tl = tid - 128, du = tl >> 5, b2 = tl & 31;
        float s = 0.f;
#pragma unroll
        for (int sg = 0; sg < 8; ++sg) s += glq[(du * 8 + sg) * 32 + b2];
        bst(stP(o, 65536 + ((t - 1) & 1) * 16384 + b2 * 512 + bk * 2 + du), s); // q(t-1)
      }
    } else {
      if (t >= 1 && t <= T_STEPS) {
        int tl = tid - 192, du = tl >> 5, b2 = tl & 31;
        float s = 0.f;
#pragma unroll
        for (int sg = 0; sg < 8; ++sg) s += glo2[(du * 8 + sg) * 32 + b2];
        oph[((t - 1) & 1) * 128 + du * 32 + b2] = s;                            // oph(t-1)
      }
    }
    __syncthreads();
    // ===== attention(t-2): 8 blocks per batch, 64-component ctx slice =====
    if (t >= 2 && t <= T_STEPS + 1) {
      const int bb = bk >> 3, sl = bk & 7;
      if (tid < 128)
        *(float4*)&xs[tid * 4] =
            bld4(stP(o, 65536 + (t & 1) * 16384 + bb * 512 + tid * 4));  // q(t-2)
      __syncthreads();
      {
        int s = tid >> 2, kc = tid & 3;
        const float* crow = context + ((size_t)bb * SEQ + s) * HID + kc * 128;
        float ax = 0.f, ay = 0.f, az = 0.f, aw = 0.f;
#pragma unroll 8
        for (int i = 0; i < 32; ++i) {
          float4 c4 = *(const float4*)(crow + i * 4);
          const float* q4 = &xs[kc * 128 + i * 4];
          ax += c4.x * q4[0]; ay += c4.y * q4[1];
          az += c4.z * q4[2]; aw += c4.w * q4[3];
        }
        glL1[tid] = (ax + ay) + (az + aw);
      }
      __syncthreads();
      if (tid < 64) {
        float sc = glL1[tid * 4] + glL1[tid * 4 + 1] + glL1[tid * 4 + 2] + glL1[tid * 4 + 3];
        float m = sc;
#pragma unroll
        for (int off = 32; off > 0; off >>= 1) m = fmaxf(m, __shfl_xor(m, off));
        float e = expf(sc - m);
        float su = e;
#pragma unroll
        for (int off = 32; off > 0; off >>= 1) su += __shfl_xor(su, off);
        float av = e / su;
        at_s[tid] = av;
        if (t == T_STEPS + 1 && sl == 0) o_attn[bb * SEQ + tid] = av;  // attn(63)
      }
      __syncthreads();
      {
        int h = sl * 64 + (tid & 63), sh = tid >> 6;
        const float* cb = context + (size_t)bb * SEQ * HID + h;
        float a2 = 0.f;
#pragma unroll 8
        for (int s2 = sh * 16; s2 < sh * 16 + 16; ++s2)
          a2 += at_s[s2] * cb[(size_t)s2 * HID];
        gloC[tid] = a2;
      }
      __syncthreads();
      if (tid < 64)
        bst(stP(o, 98304 + (t & 1) * 16384 + bb * 512 + sl * 64 + tid),
            gloC[tid] + gloC[tid + 64] + gloC[tid + 128] + gloC[tid + 192]); // ctx(t-2)
    }
    gsync(o, ++g);
  }

  // ===== final states =====
  if (tid < 64) {
    int b2 = tid & 31, du = tid >> 5, u = bk * 2 + du;
    o_h[b2 * 512 + u]         = bld(stP(o, 16384 + b2 * 512 + u));    // h0(63) buf1
    o_h[16384 + b2 * 512 + u] = bld(stP(o, 49152 + b2 * 512 + u));    // h1(63) buf1
    o_c[b2 * 512 + u]         = c0s[du * 32 + b2];
    o_c[16384 + b2 * 512 + u] = c1s[du * 32 + b2];
  }
}

// ---------------------------------------------------------------------------
// vocab GEMM pass A: 490 col-tiles avoiding cols [16000,16640).
// ---------------------------------------------------------------------------
__device__ __forceinline__ short8 pack8(const float* p) {
  float4 a = *(const float4*)p, b = *(const float4*)(p + 4);
  short8 r;
  r[0] = (short)f2bf(a.x); r[1] = (short)f2bf(a.y);
  r[2] = (short)f2bf(a.z); r[3] = (short)f2bf(a.w);
  r[4] = (short)f2bf(b.x); r[5] = (short)f2bf(b.y);
  r[6] = (short)f2bf(b.z); r[7] = (short)f2bf(b.w);
  return r;
}

__global__ __launch_bounds__(256) void vocab_gemm_a(
    float* o, const float* __restrict__ Bw, const float* __restrict__ bias)
{
  __shared__ __align__(16) u16 As[4 * 64 * 8];
  __shared__ __align__(16) u16 Bs[4 * 64 * 8];
  const int tid = threadIdx.x;
  const int wv   = tid >> 6;
  const int lane = tid & 63;
  const int m16  = lane & 15;
  const int quad = lane >> 4;
  const int ct = (blockIdx.x < 250) ? blockIdx.x : blockIdx.x + 10;
  const int rowBase = blockIdx.y * 64;
  const int colBase = ct * 64;
  const int srow = tid >> 2;
  const int scg  = tid & 3;
  f32x4 acc[4];
#pragma unroll
  for (int nt = 0; nt < 4; ++nt)
#pragma unroll
    for (int r = 0; r < 4; ++r) acc[nt][r] = 0.f;

  for (int k0 = 0; k0 < HID; k0 += 32) {
    __syncthreads();
    *(short8*)&As[(scg * 64 + srow) * 8] =
        pack8(&o[(size_t)(rowBase + srow) * VOCAB + ABASE + k0 + scg * 8]);
    *(short8*)&Bs[(scg * 64 + srow) * 8] =
        pack8(&Bw[(size_t)(colBase + srow) * HID + k0 + scg * 8]);
    __syncthreads();
    short8 a = *(const short8*)&As[(quad * 64 + wv * 16 + m16) * 8];
#pragma unroll
    for (int nt = 0; nt < 4; ++nt) {
      short8 bfr = *(const short8*)&Bs[(quad * 64 + nt * 16 + m16) * 8];
      acc[nt] = __builtin_amdgcn_mfma_f32_16x16x32_bf16(a, bfr, acc[nt], 0, 0, 0);
    }
  }
#pragma unroll
  for (int nt = 0; nt < 4; ++nt) {
    int col = colBase + nt * 16 + m16;
    float bv = bias[col];
#pragma unroll
    for (int r = 0; r < 4; ++r) {
      int row = rowBase + wv * 16 + quad * 4 + r;
      o[(size_t)row * VOCAB + col] = acc[nt][r] + bv;
    }
  }
}

// ---------------------------------------------------------------------------
// pass B: the 10 band col-tiles. A staged to LDS BEFORE any write.
// ---------------------------------------------------------------------------
__global__ __launch_bounds__(256) void vocab_gemm_b(
    float* o, const float* __restrict__ Bw, const float* __restrict__ bias)
{
  __shared__ __align__(16) u16 As[32 * 512];   // 32 KB bf16
  const int tid = threadIdx.x;
  const int rowBase = blockIdx.x * 32;
  for (int i = tid; i < 2048; i += 256) {      // 2048 chunks of 8
    int r = i >> 6, kk = (i & 63) * 8;
    *(short8*)&As[r * 512 + kk] =
        pack8(&o[(size_t)(rowBase + r) * VOCAB + ABASE + kk]);
  }
  __syncthreads();
  const int lane = tid & 63, w = tid >> 6;
  const int m16 = lane & 15, quad = lane >> 4;
  const int rg = w & 1, cg = w >> 1;
  for (int ctile = 250; ctile < 260; ++ctile) {
    int colBase = ctile * 64 + cg * 32;
    f32x4 acc[2];
#pragma unroll
    for (int nt = 0; nt < 2; ++nt)
#pragma unroll
      for (int r = 0; r < 4; ++r) acc[nt][r] = 0.f;
    for (int k0 = 0; k0 < HID; k0 += 32) {
      short8 a = *(const short8*)&As[(rg * 16 + m16) * 512 + k0 + quad * 8];
#pragma unroll
      for (int nt = 0; nt < 2; ++nt) {
        short8 bfr = pack8(&Bw[(size_t)(colBase + nt * 16 + m16) * HID + k0 + quad * 8]);
        acc[nt] = __builtin_amdgcn_mfma_f32_16x16x32_bf16(a, bfr, acc[nt], 0, 0, 0);
      }
    }
#pragma unroll
    for (int nt = 0; nt < 2; ++nt) {
      int col = colBase + nt * 16 + m16;
      float bv = bias[col];
#pragma unroll
      for (int r = 0; r < 4; ++r) {
        int row = rowBase + rg * 16 + quad * 4 + r;
        o[(size_t)row * VOCAB + col] = acc[nt][r] + bv;
      }
    }
  }
}

// ---------------------------------------------------------------------------
// log-softmax over V=32000, 3-pass global (rows are L2/L3-hot)
// ---------------------------------------------------------------------------
__global__ __launch_bounds__(256) void logsoftmax_kernel(float* logits)
{
  __shared__ float red[256];
  const int tid = threadIdx.x;
  float* rowp = logits + (size_t)blockIdx.x * VOCAB;
  float mx = -1e30f;
  for (int i = tid; i < VOCAB / 4; i += 256) {
    float4 v = ((const float4*)rowp)[i];
    mx = fmaxf(mx, fmaxf(fmaxf(v.x, v.y), fmaxf(v.z, v.w)));
  }
  red[tid] = mx; __syncthreads();
  for (int s = 128; s > 0; s >>= 1) {
    if (tid < s) red[tid] = fmaxf(red[tid], red[tid + s]);
    __syncthreads();
  }
  mx = red[0]; __syncthreads();
  float sum = 0.f;
  for (int i = tid; i < VOCAB / 4; i += 256) {
    float4 v = ((const float4*)rowp)[i];
    sum += expf(v.x - mx) + expf(v.y - mx) + expf(v.z - mx) + expf(v.w - mx);
  }
  red[tid] = sum; __syncthreads();
  for (int s = 128; s > 0; s >>= 1) {
    if (tid < s) red[tid] += red[tid + s];
    __syncthreads();
  }
  float lse = mx + logf(red[0]);
  for (int i = tid; i < VOCAB / 4; i += 256) {
    float4 v = ((const float4*)rowp)[i];
    float4 ov;
    ov.x = v.x - lse; ov.y = v.y - lse; ov.z = v.z - lse; ov.w = v.w - lse;
    ((float4*)rowp)[i] = ov;
  }
}

// ---------------------------------------------------------------------------
extern "C" void kernel_launch(void* const* d_in, const int* in_sizes, int n_in,
                              void* d_out, int out_size, void* d_ws, size_t ws_size,
                              hipStream_t stream)
{
  (void)in_sizes; (void)n_in; (void)out_size; (void)d_ws; (void)ws_size;
  const int*   tokens  = (const int*)d_in[0];
  const float* h0      = (const float*)d_in[1];
  const float* c0      = (const float*)d_in[2];
  const float* context = (const float*)d_in[3];
  const float* emb     = (const float*)d_in[4];
  const float* Wih     = (const float*)d_in[5];
  const float* Whh     = (const float*)d_in[6];
  const float* bih     = (const float*)d_in[7];
  const float* bhh     = (const float*)d_in[8];
  const float* Wai     = (const float*)d_in[9];
  const float* Wao     = (const float*)d_in[10];
  const float* Wlin    = (const float*)d_in[11];
  const float* blin    = (const float*)d_in[12];

  float* o      = (float*)d_out;
  float* o_h    = o + (size_t)2048 * VOCAB;
  float* o_c    = o_h + 32768;
  float* o_attn = o_c + 32768;

  // zero the sync words (rows 0..5, col 17024; overwritten later by gemm_a)
  for (int r = 0; r < 6; ++r)
    hipMemsetAsync(o + (size_t)r * VOCAB + 17024, 0, 256, stream);

  hipFuncSetAttribute((const void*)persist_kernel,
                      hipFuncAttributeMaxDynamicSharedMemorySize, SMEM_BYTES);
  persist_kernel<<<NBLK, 256, SMEM_BYTES, stream>>>(
      o, tokens, emb, Wih, Whh, bih, bhh, Wai, Wao,
      h0, c0, context, o_h, o_c, o_attn);

  vocab_gemm_a<<<dim3(490, 32), 256, 0, stream>>>(o, Wlin, blin);
  vocab_gemm_b<<<64, 256, 0, stream>>>(o, Wlin, blin);
  logsoftmax_kernel<<<2048, 256, 0, stream>>>(o);
}